// Round 1
// baseline (293.729 us; speedup 1.0000x reference)
//
#include <hip/hip_runtime.h>
#include <hip/hip_fp16.h>

// ForwardDeformer (B=4, N=250000, J=55, vol [55,16,64,64]).
// R1: pre-blend voxel grid with matrices (linearity) -> per-voxel 4x4 mats.
// R4 post-mortem: global compaction -> scattered 64B writes -> partial-line RMW.
// R5: natural order, team=point lane=batch. 111.6us: DS-pipe bound — every
// wave executes BOTH mask branches (random mask -> mixed teams per wave);
// masked body is 275 ds_read_b128/lane, unmasked adds 176 shfl.
// R6: (a) block-local mask partition via wave-0 ballot -> perm[64] in LDS;
// teams process permuted points so waves are mask-uniform (masked LDS storm
// issued by only ~half the waves; writes stay in 64-pt windows so L2 still
// write-combines). (b) unmasked: acc all 4 batches in regs then 2-stage XOR
// butterfly transpose (32 shfl) instead of 128 scatter shfls.

#define JNT 55
#define VD  16
#define VH  64
#define VW  64
#define NVOX (VD * VH * VW)   // 65536

// ---------------------------------------------------------------------------
// Pre-pass: tab[(b*NVOX+v)] = 64B entry { half Mi[16], half Mv_b[16] }.
// ---------------------------------------------------------------------------
__global__ __launch_bounds__(256, 2) void build_tab_k(
    const float* __restrict__ vol, const float* __restrict__ tfs,
    const float* __restrict__ tfs_inv, __half* __restrict__ tab)
{
    int v = blockIdx.x * 256 + threadIdx.x;
    int b = blockIdx.y;
    if (v >= NVOX) return;
    float w[JNT];
#pragma unroll
    for (int j = 0; j < JNT; ++j) w[j] = vol[j * NVOX + v];

    float Mi[16], Mv[16];
#pragma unroll
    for (int i = 0; i < 16; ++i) { Mi[i] = 0.f; Mv[i] = 0.f; }
    const float* tb = tfs + (size_t)b * JNT * 16;
#pragma unroll
    for (int j = 0; j < JNT; ++j) {
        float wj = w[j];
#pragma unroll
        for (int i = 0; i < 16; ++i) Mi[i] = fmaf(wj, tfs_inv[j * 16 + i], Mi[i]);
#pragma unroll
        for (int i = 0; i < 16; ++i) Mv[i] = fmaf(wj, tb[j * 16 + i], Mv[i]);
    }
    float h[16];
#pragma unroll
    for (int i = 0; i < 8; ++i)
        h[i] = __builtin_bit_cast(float, __floats2half2_rn(Mi[2*i], Mi[2*i+1]));
#pragma unroll
    for (int i = 0; i < 8; ++i)
        h[8+i] = __builtin_bit_cast(float, __floats2half2_rn(Mv[2*i], Mv[2*i+1]));

    float4* d4 = (float4*)(tab + ((size_t)b * NVOX + v) * 32);
    d4[0] = make_float4(h[0],  h[1],  h[2],  h[3]);
    d4[1] = make_float4(h[4],  h[5],  h[6],  h[7]);
    d4[2] = make_float4(h[8],  h[9],  h[10], h[11]);
    d4[3] = make_float4(h[12], h[13], h[14], h[15]);
}

// Accumulate 8 fp16 values (one float4 of packed half2) into a[0..7].
__device__ __forceinline__ void acc8(float cw, float4 r, float* a)
{
    float rr[4] = {r.x, r.y, r.z, r.w};
#pragma unroll
    for (int kk = 0; kk < 4; ++kk) {
        __half2 h = __builtin_bit_cast(__half2, rr[kk]);
        float2 f = __half22float2(h);
        a[2*kk]     = fmaf(cw, f.x, a[2*kk]);
        a[2*kk + 1] = fmaf(cw, f.y, a[2*kk + 1]);
    }
}

__device__ __forceinline__ void epilogue(
    int b, int n, int N, float x, float y, float z,
    const float* A, const float* Ai,
    const float* __restrict__ shoff, const float* __restrict__ pooff,
    const float* __restrict__ poori,
    float* __restrict__ out_xd, float* __restrict__ out_w)
{
    size_t pid = (size_t)b * N + n;
    size_t p3  = pid * 3;
    size_t n3  = (size_t)n * 3;
    float c0 = Ai[0]*x + Ai[1]*y + Ai[2]*z  + Ai[3];
    float c1 = Ai[4]*x + Ai[5]*y + Ai[6]*z  + Ai[7];
    float c2 = Ai[8]*x + Ai[9]*y + Ai[10]*z + Ai[11];
    float sx = c0 - poori[n3 + 0] + shoff[p3 + 0] + pooff[p3 + 0];
    float sy = c1 - poori[n3 + 1] + shoff[p3 + 1] + pooff[p3 + 1];
    float sz = c2 - poori[n3 + 2] + shoff[p3 + 2] + pooff[p3 + 2];
    out_xd[p3 + 0] = A[0]*sx + A[1]*sy + A[2]*sz  + A[3];
    out_xd[p3 + 1] = A[4]*sx + A[5]*sy + A[6]*sz  + A[7];
    out_xd[p3 + 2] = A[8]*sx + A[9]*sy + A[10]*sz + A[11];

    float4* ow = (float4*)(out_w + pid * 16);
#pragma unroll
    for (int i = 0; i < 4; ++i) {
        float a0 = A[i*4+0], a1 = A[i*4+1], a2 = A[i*4+2], a3 = A[i*4+3];
        float4 r;
        r.x = a0*Ai[0] + a1*Ai[4] + a2*Ai[8]  + a3*Ai[12];
        r.y = a0*Ai[1] + a1*Ai[5] + a2*Ai[9]  + a3*Ai[13];
        r.z = a0*Ai[2] + a1*Ai[6] + a2*Ai[10] + a3*Ai[14];
        r.w = a0*Ai[3] + a1*Ai[7] + a2*Ai[11] + a3*Ai[15];
        ow[i] = r;
    }
}

// ---------------------------------------------------------------------------
// Main kernel: 256 threads = 64 teams of 4; team t -> point perm[t] of this
// block's 64-point window; lane k of team -> batch k. perm sorts masked
// teams first so waves are mask-uniform.
// ---------------------------------------------------------------------------
template <int B>
__global__ __launch_bounds__(256, 4) void main_k(
    const float* __restrict__ xc,
    const float* __restrict__ shoff,
    const float* __restrict__ pooff,
    const float* __restrict__ tfs,        // [B, J, 16]
    const float* __restrict__ tfs_inv,    // [J, 16]
    const float* __restrict__ poori,      // [N, 3]
    const float* __restrict__ lbsw,       // [N, J]
    const int*   __restrict__ mask,       // [N]
    const __half* __restrict__ tab,       // [B, NVOX, 32 halves]
    const float* __restrict__ offk,
    const float* __restrict__ sck,
    float* __restrict__ out_xd,
    float* __restrict__ out_w,
    int N)
{
    __shared__ float sTi[JNT * 16];       // [j][16]
    __shared__ float sT[JNT * B * 16];    // [j][b][16]
    __shared__ unsigned char sPerm[64];
    __shared__ int sNm;

    int tx = threadIdx.x;
    for (int t = tx; t < JNT * 16; t += 256) sTi[t] = tfs_inv[t];
    for (int t = tx; t < JNT * B * 16; t += 256) {
        int j = t >> 6, r = t & 63, b = r >> 4, i = r & 15;
        sT[t] = tfs[((size_t)b * JNT + j) * 16 + i];
    }
    // wave 0 builds the mask partition for this block's 64 points
    if (tx < 64) {
        int n0 = blockIdx.x * 64 + tx;
        bool mm = (n0 < N) && (mask[n0] != 0);
        unsigned long long bal = __ballot(mm);
        int nm = __popcll(bal);
        unsigned long long below = bal & ((1ull << tx) - 1ull);
        int pos = mm ? __popcll(below) : (nm + (tx - __popcll(below)));
        sPerm[pos] = (unsigned char)tx;
        if (tx == 0) sNm = nm;
    }
    __syncthreads();

    int team = tx >> 2, k = tx & 3;
    int lane = tx & 63, qb = lane & ~3;
    int slot = sPerm[team];
    int n = blockIdx.x * 64 + slot;
    bool m = (team < sNm);            // masked teams sorted first
    if (n >= N) return;               // invalid slots live in unmasked tail

    size_t p3 = ((size_t)k * N + n) * 3;
    float x = xc[p3], y = xc[p3 + 1], z = xc[p3 + 2];

    // res = [Ai(16) | A(16)] for (point n, batch k)
    float res[32];

    if (m) {
        // -------- masked: lane k owns A_k[16] + Ai row k; coop w load -------
        float wl[14];
        const float* row = lbsw + (size_t)n * JNT;
#pragma unroll
        for (int i = 0; i < 14; ++i) {
            int j = 4 * i + k;
            wl[i] = (j < JNT) ? row[j] : 0.f;
        }
        float AiR[4] = {0.f, 0.f, 0.f, 0.f};
#pragma unroll
        for (int i = 0; i < 16; ++i) res[16 + i] = 0.f;

#pragma unroll
        for (int i = 0; i < 14; ++i) {
#pragma unroll
            for (int k2 = 0; k2 < 4; ++k2) {
                int j = 4 * i + k2;
                if (j >= JNT) continue;
                float wj = __shfl(wl[i], qb + k2);
                float4 ti = *(const float4*)(sTi + j * 16 + 4 * k);
                AiR[0] = fmaf(wj, ti.x, AiR[0]);
                AiR[1] = fmaf(wj, ti.y, AiR[1]);
                AiR[2] = fmaf(wj, ti.z, AiR[2]);
                AiR[3] = fmaf(wj, ti.w, AiR[3]);
                const float* tb = sT + (j * B + k) * 16;
#pragma unroll
                for (int q = 0; q < 4; ++q) {
                    float4 r = *(const float4*)(tb + 4 * q);
                    res[16 + 4*q + 0] = fmaf(wj, r.x, res[16 + 4*q + 0]);
                    res[16 + 4*q + 1] = fmaf(wj, r.y, res[16 + 4*q + 1]);
                    res[16 + 4*q + 2] = fmaf(wj, r.z, res[16 + 4*q + 2]);
                    res[16 + 4*q + 3] = fmaf(wj, r.w, res[16 + 4*q + 3]);
                }
            }
        }
        // reconstruct full Ai from row-split
#pragma unroll
        for (int r = 0; r < 4; ++r)
#pragma unroll
            for (int i = 0; i < 4; ++i)
                res[r * 4 + i] = __shfl(AiR[i], qb + r);
    } else {
        // -------- unmasked: team gather per b (1 line/corner), then one -----
        // -------- 2-stage XOR butterfly quad-transpose at the end -----------
        float o0 = offk[0], o1 = offk[1], o2 = offk[2];
        float s0 = sck[0],  s1 = sck[1],  s2 = sck[2];
#pragma unroll
        for (int i = 0; i < 32; ++i) res[i] = 0.f;

#pragma unroll
        for (int b = 0; b < B; ++b) {
            float xb = __shfl(x, qb + b);
            float yb = __shfl(y, qb + b);
            float zb = __shfl(z, qb + b);
            float px = (xb + o0) * s0;
            float py = (yb + o1) * s1;
            float pz = (zb + o2) * s2;
            float ix = fminf(fmaxf((px + 1.f) * 0.5f * (VW - 1), 0.f), (float)(VW - 1));
            float iy = fminf(fmaxf((py + 1.f) * 0.5f * (VH - 1), 0.f), (float)(VH - 1));
            float iz = fminf(fmaxf((pz + 1.f) * 0.5f * (VD - 1), 0.f), (float)(VD - 1));
            float fx = floorf(ix), fy = floorf(iy), fz = floorf(iz);
            float wx = ix - fx,    wy = iy - fy,    wz = iz - fz;
            int x0 = (int)fx, y0 = (int)fy, z0 = (int)fz;
            int x1 = min(x0 + 1, VW - 1);
            int y1 = min(y0 + 1, VH - 1);
            int z1 = min(z0 + 1, VD - 1);
            float cwx[2] = {1.f - wx, wx};
            float cwy[2] = {1.f - wy, wy};
            float cwz[2] = {1.f - wz, wz};
            int   xs[2] = {x0, x1}, ys[2] = {y0, y1}, zs[2] = {z0, z1};

            const __half* tbb = tab + (size_t)b * NVOX * 32;
#pragma unroll
            for (int c = 0; c < 8; ++c) {
                int cz = c >> 2, cy = (c >> 1) & 1, cx = c & 1;
                int vox = (zs[cz] * VH + ys[cy]) * VW + xs[cx];
                float cw = cwz[cz] * cwy[cy] * cwx[cx];
                float4 r4 = ((const float4*)(tbb + (size_t)vox * 32))[k];
                acc8(cw, r4, res + b * 8);   // lane k holds quarter k of batch b
            }
        }
        // butterfly: res[q*8+i] (quarter k, batch q) -> (quarter q, batch k)
        // stage 1: exchange with lane^1, pairs (0,1) and (2,3)
        {
            int p1 = lane ^ 1;
            bool odd = (k & 1) != 0;
#pragma unroll
            for (int pb = 0; pb < 4; pb += 2) {
#pragma unroll
                for (int i = 0; i < 8; ++i) {
                    float send = odd ? res[pb*8 + i] : res[(pb+1)*8 + i];
                    float got  = __shfl(send, p1);
                    float nb   = odd ? got : res[pb*8 + i];
                    float nb1  = odd ? res[(pb+1)*8 + i] : got;
                    res[pb*8 + i]     = nb;
                    res[(pb+1)*8 + i] = nb1;
                }
            }
        }
        // stage 2: exchange with lane^2, pairs (0,2) and (1,3)
        {
            int p2 = lane ^ 2;
            bool hi = (k & 2) != 0;
#pragma unroll
            for (int pb = 0; pb < 2; ++pb) {
#pragma unroll
                for (int i = 0; i < 8; ++i) {
                    float send = hi ? res[pb*8 + i] : res[(pb+2)*8 + i];
                    float got  = __shfl(send, p2);
                    float nb   = hi ? got : res[pb*8 + i];
                    float nb2  = hi ? res[(pb+2)*8 + i] : got;
                    res[pb*8 + i]     = nb;
                    res[(pb+2)*8 + i] = nb2;
                }
            }
        }
    }

    epilogue(k, n, N, x, y, z, res + 16, res, shoff, pooff, poori, out_xd, out_w);
}

// ---------------------------------------------------------------------------
// Fallback (ws too small or B != 4): per-thread direct gather from vol.
// ---------------------------------------------------------------------------
__global__ __launch_bounds__(256) void fb_k(
    const float* __restrict__ xc, const float* __restrict__ shoff,
    const float* __restrict__ pooff, const float* __restrict__ tfs,
    const float* __restrict__ tfs_inv, const float* __restrict__ poori,
    const float* __restrict__ lbsw, const int* __restrict__ mask,
    const float* __restrict__ vol, const float* __restrict__ offk,
    const float* __restrict__ sck, float* __restrict__ out_xd,
    float* __restrict__ out_w, int N)
{
    int n = blockIdx.x * 256 + threadIdx.x;
    int b = blockIdx.y;
    if (n >= N) return;
    size_t p3 = ((size_t)b * N + n) * 3;
    float x = xc[p3], y = xc[p3 + 1], z = xc[p3 + 2];
    float A[16], Ai[16];
#pragma unroll
    for (int i = 0; i < 16; ++i) { A[i] = 0.f; Ai[i] = 0.f; }
    const float* tb = tfs + (size_t)b * JNT * 16;

    if (mask[n] != 0) {
        const float* lp = lbsw + (size_t)n * JNT;
        for (int j = 0; j < JNT; ++j) {
            float wj = lp[j];
#pragma unroll
            for (int i = 0; i < 16; ++i) Ai[i] = fmaf(wj, tfs_inv[j*16+i], Ai[i]);
#pragma unroll
            for (int i = 0; i < 16; ++i) A[i]  = fmaf(wj, tb[j*16+i],      A[i]);
        }
    } else {
        float px = (x + offk[0]) * sck[0];
        float py = (y + offk[1]) * sck[1];
        float pz = (z + offk[2]) * sck[2];
        float ix = fminf(fmaxf((px + 1.f) * 0.5f * (VW - 1), 0.f), (float)(VW - 1));
        float iy = fminf(fmaxf((py + 1.f) * 0.5f * (VH - 1), 0.f), (float)(VH - 1));
        float iz = fminf(fmaxf((pz + 1.f) * 0.5f * (VD - 1), 0.f), (float)(VD - 1));
        float fx = floorf(ix), fy = floorf(iy), fz = floorf(iz);
        float wx = ix - fx, wy = iy - fy, wz = iz - fz;
        int x0 = (int)fx, y0 = (int)fy, z0 = (int)fz;
        int x1 = min(x0 + 1, VW - 1);
        int y1 = min(y0 + 1, VH - 1);
        int z1 = min(z0 + 1, VD - 1);
        float w00 = (1.f - wz) * (1.f - wy), w01 = (1.f - wz) * wy;
        float w10 = wz * (1.f - wy),         w11 = wz * wy;
        int o00 = (z0 * VH + y0) * VW, o01 = (z0 * VH + y1) * VW;
        int o10 = (z1 * VH + y0) * VW, o11 = (z1 * VH + y1) * VW;
        for (int j = 0; j < JNT; ++j) {
            const float* vp = vol + (size_t)j * NVOX;
            float v000 = vp[o00 + x0], v001 = vp[o00 + x1];
            float v010 = vp[o01 + x0], v011 = vp[o01 + x1];
            float v100 = vp[o10 + x0], v101 = vp[o10 + x1];
            float v110 = vp[o11 + x0], v111 = vp[o11 + x1];
            float c0 = w00 * v000 + w01 * v010 + w10 * v100 + w11 * v110;
            float c1 = w00 * v001 + w01 * v011 + w10 * v101 + w11 * v111;
            float wj = c0 + wx * (c1 - c0);
#pragma unroll
            for (int i = 0; i < 16; ++i) Ai[i] = fmaf(wj, tfs_inv[j*16+i], Ai[i]);
#pragma unroll
            for (int i = 0; i < 16; ++i) A[i]  = fmaf(wj, tb[j*16+i],      A[i]);
        }
    }
    epilogue(b, n, N, x, y, z, A, Ai, shoff, pooff, poori, out_xd, out_w);
}

extern "C" void kernel_launch(void* const* d_in, const int* in_sizes, int n_in,
                              void* d_out, int out_size, void* d_ws, size_t ws_size,
                              hipStream_t stream)
{
    const float* xc    = (const float*)d_in[0];
    const float* shoff = (const float*)d_in[1];
    const float* pooff = (const float*)d_in[2];
    const float* tfs   = (const float*)d_in[3];
    const float* tfsi  = (const float*)d_in[4];
    const float* poori = (const float*)d_in[5];
    const float* lbsw  = (const float*)d_in[6];
    const int*   mask  = (const int*)d_in[7];
    const float* vol   = (const float*)d_in[8];
    const float* offk  = (const float*)d_in[9];
    const float* sck   = (const float*)d_in[10];

    int N = in_sizes[5] / 3;          // poseoff_ori [1,N,3]
    int B = in_sizes[0] / (3 * N);    // xc [B,N,3]
    float* out_xd = (float*)d_out;
    float* out_w  = (float*)d_out + (size_t)B * N * 3;

    size_t tab_bytes = (size_t)B * NVOX * 32 * sizeof(__half);  // 16.78 MB
    __half* tab = (__half*)d_ws;

    if (B == 4 && ws_size >= tab_bytes) {
        build_tab_k<<<dim3((NVOX + 255) / 256, 4), dim3(256), 0, stream>>>(
            vol, tfs, tfsi, tab);
        main_k<4><<<dim3((N + 63) / 64), dim3(256), 0, stream>>>(
            xc, shoff, pooff, tfs, tfsi, poori, lbsw, mask, tab,
            offk, sck, out_xd, out_w, N);
    } else {
        fb_k<<<dim3((N + 255) / 256, B), dim3(256), 0, stream>>>(
            xc, shoff, pooff, tfs, tfsi, poori, lbsw, mask, vol, offk, sck,
            out_xd, out_w, N);
    }
}